// Round 1
// baseline (1882.121 us; speedup 1.0000x reference)
//
#include <hip/hip_runtime.h>

#define NN 50000
#define EE 800000
#define RR 8
// F_IN == H == 128

// ---------------- GEMM: C = act(A) @ B (+ bias) ----------------
// A [M,128] row-major, B [128,128] row-major, C [M,128].
// BM=64, BN=128, BK=32; 256 threads; each thread: 8 rows x 4 cols.
template<bool RELU_IN, bool ADD_BIAS>
__global__ __launch_bounds__(256) void gemm128(
    const float* __restrict__ A, const float* __restrict__ B,
    const float* __restrict__ bias, float* __restrict__ C, int M)
{
    __shared__ float As[64][36];   // [m][k], padded to 36 to keep writes spread
    __shared__ float Bs[32][128];  // [k][n]
    const int t   = threadIdx.x;
    const int row0 = blockIdx.x * 64;
    const int tx = t & 31;         // cols tx*4 .. tx*4+3
    const int ty = t >> 5;         // rows ty*8 .. ty*8+7

    float acc[8][4];
    #pragma unroll
    for (int j = 0; j < 8; ++j)
        #pragma unroll
        for (int i = 0; i < 4; ++i) acc[j][i] = 0.f;

    for (int k0 = 0; k0 < 128; k0 += 32) {
        // Load A tile: 64x32 floats -> 512 float4, 2 per thread
        #pragma unroll
        for (int i = 0; i < 2; ++i) {
            int q  = t + i * 256;     // 0..511
            int m  = q >> 3;          // 8 float4 per row
            int kq = q & 7;
            float4 v = make_float4(0.f, 0.f, 0.f, 0.f);
            int gr = row0 + m;
            if (gr < M) v = *reinterpret_cast<const float4*>(A + (size_t)gr * 128 + k0 + kq * 4);
            if (RELU_IN) {
                v.x = fmaxf(v.x, 0.f); v.y = fmaxf(v.y, 0.f);
                v.z = fmaxf(v.z, 0.f); v.w = fmaxf(v.w, 0.f);
            }
            *reinterpret_cast<float4*>(&As[m][kq * 4]) = v;
        }
        // Load B tile: 32x128 floats -> 1024 float4, 4 per thread
        #pragma unroll
        for (int i = 0; i < 4; ++i) {
            int q  = t + i * 256;     // 0..1023
            int k  = q >> 5;          // 32 float4 per row
            int nq = q & 31;
            float4 v = *reinterpret_cast<const float4*>(B + (size_t)(k0 + k) * 128 + nq * 4);
            *reinterpret_cast<float4*>(&Bs[k][nq * 4]) = v;
        }
        __syncthreads();
        #pragma unroll
        for (int k = 0; k < 32; ++k) {
            float b0[4];
            *reinterpret_cast<float4*>(b0) = *reinterpret_cast<const float4*>(&Bs[k][tx * 4]);
            #pragma unroll
            for (int j = 0; j < 8; ++j) {
                float a = As[ty * 8 + j][k];
                acc[j][0] = fmaf(a, b0[0], acc[j][0]);
                acc[j][1] = fmaf(a, b0[1], acc[j][1]);
                acc[j][2] = fmaf(a, b0[2], acc[j][2]);
                acc[j][3] = fmaf(a, b0[3], acc[j][3]);
            }
        }
        __syncthreads();
    }
    #pragma unroll
    for (int j = 0; j < 8; ++j) {
        int gr = row0 + ty * 8 + j;
        if (gr < M) {
            float4 v;
            v.x = acc[j][0]; v.y = acc[j][1]; v.z = acc[j][2]; v.w = acc[j][3];
            if (ADD_BIAS) {
                v.x += bias[tx * 4 + 0]; v.y += bias[tx * 4 + 1];
                v.z += bias[tx * 4 + 2]; v.w += bias[tx * 4 + 3];
            }
            *reinterpret_cast<float4*>(C + (size_t)gr * 128 + tx * 4) = v;
        }
    }
}

// ---------------- degree count ----------------
__global__ void zero_i32(int* __restrict__ p, int n) {
    int i = blockIdx.x * blockDim.x + threadIdx.x;
    if (i < n) p[i] = 0;
}

__global__ void count_deg(const int* __restrict__ dst, const int* __restrict__ et,
                          int* __restrict__ deg) {
    int e = blockIdx.x * blockDim.x + threadIdx.x;
    if (e < EE) atomicAdd(&deg[dst[e] * RR + et[e]], 1);
}

// ---------------- edge aggregation ----------------
// xw: [rcount][N][128] transformed features for relations rbase..rbase+rcount-1
// out[dst] += xw[et-rbase][src] / deg[dst*R+et]
__global__ __launch_bounds__(256) void agg_edges(
    const float* __restrict__ xw,
    const int* __restrict__ src, const int* __restrict__ dst,
    const int* __restrict__ et, const int* __restrict__ deg,
    float* __restrict__ out, int rbase, int rcount)
{
    const int sub = threadIdx.x >> 7;   // 0 or 1 (edge within pair)
    const int h   = threadIdx.x & 127;
    for (long long e0 = (long long)blockIdx.x * 2; e0 < EE; e0 += (long long)gridDim.x * 2) {
        int e = (int)e0 + sub;
        if (e >= EE) continue;
        int r = et[e] - rbase;
        if ((unsigned)r >= (unsigned)rcount) continue;
        int s = src[e], d = dst[e];
        float norm = 1.0f / (float)deg[d * RR + (r + rbase)];
        float val = xw[((size_t)r * NN + s) * 128 + h] * norm;
        atomicAdd(&out[(size_t)d * 128 + h], val);
    }
}

// ---------------- final FC: out[n] = relu(h[n]) . fc_w + fc_b ----------------
__global__ __launch_bounds__(256) void final_fc(
    const float* __restrict__ h, const float* __restrict__ fcw,
    const float* __restrict__ fcb, float* __restrict__ out)
{
    int wid  = (int)((blockIdx.x * 256 + threadIdx.x) >> 6);  // one wave per node
    int lane = threadIdx.x & 63;
    if (wid >= NN) return;
    float v = fmaxf(h[(size_t)wid * 128 + lane], 0.f) * fcw[lane]
            + fmaxf(h[(size_t)wid * 128 + 64 + lane], 0.f) * fcw[64 + lane];
    #pragma unroll
    for (int off = 32; off > 0; off >>= 1) v += __shfl_down(v, off);
    if (lane == 0) out[wid] = v + fcb[0];
}

extern "C" void kernel_launch(void* const* d_in, const int* in_sizes, int n_in,
                              void* d_out, int out_size, void* d_ws, size_t ws_size,
                              hipStream_t stream) {
    const float* x     = (const float*)d_in[0];
    const int*   ei    = (const int*)d_in[1];
    const int*   etype = (const int*)d_in[2];
    const float* W[3]    = {(const float*)d_in[3], (const float*)d_in[6], (const float*)d_in[9]};
    const float* root[3] = {(const float*)d_in[4], (const float*)d_in[7], (const float*)d_in[10]};
    const float* bias[3] = {(const float*)d_in[5], (const float*)d_in[8], (const float*)d_in[11]};
    const float* fcw = (const float*)d_in[12];
    const float* fcb = (const float*)d_in[13];
    const int* src = ei;
    const int* dst = ei + EE;

    char* ws = (char*)d_ws;
    const size_t NH = (size_t)NN * 128 * sizeof(float);   // 25.6 MB
    float* hA = (float*)ws;            ws += NH;
    float* hB = (float*)ws;            ws += NH;
    int*   deg = (int*)ws;             ws += (size_t)NN * RR * sizeof(int);
    float* xw = (float*)ws;
    size_t used = 2 * NH + (size_t)NN * RR * sizeof(int);
    int nbuf = 1;
    if (ws_size > used + NH) {
        size_t remain = ws_size - used;
        nbuf = (int)(remain / NH);
        if (nbuf > 8) nbuf = 8;
        if (nbuf < 1) nbuf = 1;
    }

    // degree (graph-only, reused across layers)
    zero_i32<<<(NN * RR + 255) / 256, 256, 0, stream>>>(deg, NN * RR);
    count_deg<<<(EE + 255) / 256, 256, 0, stream>>>(dst, etype, deg);

    const int gemmGrid = (NN + 63) / 64;
    float* bufs[2] = {hA, hB};
    const float* in = x;
    for (int l = 0; l < 3; ++l) {
        float* outb = bufs[l & 1];
        bool relu = (l > 0);
        if (relu) gemm128<true, true><<<gemmGrid, 256, 0, stream>>>(in, root[l], bias[l], outb, NN);
        else      gemm128<false, true><<<gemmGrid, 256, 0, stream>>>(in, root[l], bias[l], outb, NN);
        for (int rb = 0; rb < RR; rb += nbuf) {
            int rc = RR - rb; if (rc > nbuf) rc = nbuf;
            for (int r = 0; r < rc; ++r) {
                const float* Br = W[l] + (size_t)(rb + r) * 128 * 128;
                float* xwr = xw + (size_t)r * NN * 128;
                if (relu) gemm128<true, false><<<gemmGrid, 256, 0, stream>>>(in, Br, nullptr, xwr, NN);
                else      gemm128<false, false><<<gemmGrid, 256, 0, stream>>>(in, Br, nullptr, xwr, NN);
            }
            agg_edges<<<2048, 256, 0, stream>>>(xw, src, dst, etype, deg, outb, rb, rc);
        }
        in = outb;
    }

    // final: in == bufs[0] (hA) after 3 layers
    final_fc<<<(NN * 64 + 255) / 256, 256, 0, stream>>>(in, fcw, fcb, (float*)d_out);
}

// Round 2
// 475.997 us; speedup vs baseline: 3.9541x; 3.9541x over previous
//
#include <hip/hip_runtime.h>

#define NN 50000
#define NPAD 50048           // padded to multiple of 64 rows
#define EE 800000
#define RR 8
#define NR (NN * RR)         // 400000 (dst,rel) segments
#define KK 1152              // 128 (root) + 8*128 (relations)

typedef __attribute__((ext_vector_type(8))) short bf16x8;
typedef __attribute__((ext_vector_type(4))) float f32x4;

__device__ __forceinline__ unsigned short f2bf(float f) {
    unsigned u = __builtin_bit_cast(unsigned, f);
    u = (u + 0x7FFF + ((u >> 16) & 1)) >> 16;   // RNE
    return (unsigned short)u;
}
__device__ __forceinline__ float bf2f(unsigned short s) {
    return __builtin_bit_cast(float, (unsigned)s << 16);
}

#define GLDS16(g, l) __builtin_amdgcn_global_load_lds( \
    (const __attribute__((address_space(1))) void*)(g), \
    (__attribute__((address_space(3))) void*)(l), 16, 0, 0)

// ---------------- graph preprocessing ----------------
__global__ void zero_i32(int* __restrict__ p, int n) {
    int i = blockIdx.x * blockDim.x + threadIdx.x;
    if (i < n) p[i] = 0;
}

__global__ void count_deg(const int* __restrict__ dst, const int* __restrict__ et,
                          int* __restrict__ deg) {
    int e = blockIdx.x * blockDim.x + threadIdx.x;
    if (e < EE) atomicAdd(&deg[dst[e] * RR + et[e]], 1);
}

// exclusive scan over n ints: 1024 per block
__global__ __launch_bounds__(256) void scan1(const int* __restrict__ in, int* __restrict__ out,
                                             int* __restrict__ bsum, int n) {
    __shared__ int sh[256];
    int t = threadIdx.x;
    int base = blockIdx.x * 1024 + t * 4;
    int v[4]; int s = 0;
    #pragma unroll
    for (int i = 0; i < 4; ++i) { int idx = base + i; v[i] = (idx < n) ? in[idx] : 0; s += v[i]; }
    sh[t] = s; __syncthreads();
    for (int off = 1; off < 256; off <<= 1) {
        int x = (t >= off) ? sh[t - off] : 0; __syncthreads();
        if (t >= off) sh[t] += x; __syncthreads();
    }
    if (t == 255) bsum[blockIdx.x] = sh[255];
    int run = sh[t] - s;
    #pragma unroll
    for (int i = 0; i < 4; ++i) { int idx = base + i; if (idx < n) out[idx] = run; run += v[i]; }
}

__global__ __launch_bounds__(256) void scan2(int* __restrict__ bsum, int nb) {
    __shared__ int sh[256];
    int t = threadIdx.x; int carry = 0;
    for (int base = 0; base < nb; base += 256) {
        int idx = base + t;
        int v = (idx < nb) ? bsum[idx] : 0;
        sh[t] = v; __syncthreads();
        for (int off = 1; off < 256; off <<= 1) {
            int x = (t >= off) ? sh[t - off] : 0; __syncthreads();
            if (t >= off) sh[t] += x; __syncthreads();
        }
        int incl = sh[t];
        int total = sh[255];
        if (idx < nb) bsum[idx] = carry + incl - v;   // exclusive
        carry += total;
        __syncthreads();
    }
}

__global__ __launch_bounds__(256) void scan3(int* __restrict__ out, const int* __restrict__ bsum, int n) {
    int base = blockIdx.x * 1024 + threadIdx.x * 4;
    int add = bsum[blockIdx.x];
    #pragma unroll
    for (int i = 0; i < 4; ++i) { int idx = base + i; if (idx < n) out[idx] += add; }
}

__global__ void set_last(int* __restrict__ segStart) {
    segStart[NR] = EE;
}

__global__ void scatter_edges(const int* __restrict__ src, const int* __restrict__ dst,
                              const int* __restrict__ et, const int* __restrict__ segStart,
                              int* __restrict__ cursor, int* __restrict__ sortedSrc) {
    int e = blockIdx.x * blockDim.x + threadIdx.x;
    if (e >= EE) return;
    int seg = dst[e] * RR + et[e];
    int pos = segStart[seg] + atomicAdd(&cursor[seg], 1);
    sortedSrc[pos] = src[e];
}

// ---------------- weight layout: Bt[col][k] = Bmat[k][col], bf16 ----------------
// Bmat rows: [0,128) = root[k][col]; [128+r*128+k'] = W[r][k'][col]
__global__ void build_bt(const float* __restrict__ W, const float* __restrict__ root,
                         unsigned short* __restrict__ Bt) {
    int i = blockIdx.x * blockDim.x + threadIdx.x;
    if (i >= 128 * KK) return;
    int col = i / KK, k = i % KK;
    float v;
    if (k < 128) v = root[k * 128 + col];
    else {
        int r = (k - 128) >> 7, kp = (k - 128) & 127;
        v = W[((size_t)r * 128 + kp) * 128 + col];
    }
    Bt[i] = f2bf(v);
}

// ---------------- aggregation: Acat[n] = [h_in(n) | mean_r(h_in[src])] ----------------
template<typename TIN>
__global__ __launch_bounds__(128) void aggregate(
    const TIN* __restrict__ hin,          // [NN][128]
    const int* __restrict__ segStart, const int* __restrict__ sortedSrc,
    unsigned short* __restrict__ Acat)    // [NPAD][1152] bf16
{
    int n = blockIdx.x;
    int h = threadIdx.x;
    size_t rowb = (size_t)n * KK;
    if (n >= NN) {
        for (int c = h; c < KK; c += 128) Acat[rowb + c] = 0;
        return;
    }
    float own;
    if constexpr (sizeof(TIN) == 4) own = ((const float*)hin)[(size_t)n * 128 + h];
    else                            own = bf2f(((const unsigned short*)hin)[(size_t)n * 128 + h]);
    Acat[rowb + h] = f2bf(own);
    int base = n * RR;
    for (int r = 0; r < RR; ++r) {
        int s0 = segStart[base + r], s1 = segStart[base + r + 1];
        float acc = 0.f;
        for (int e = s0; e < s1; ++e) {
            int s = sortedSrc[e];
            if constexpr (sizeof(TIN) == 4) acc += ((const float*)hin)[(size_t)s * 128 + h];
            else                            acc += bf2f(((const unsigned short*)hin)[(size_t)s * 128 + h]);
        }
        float out = (s1 > s0) ? acc / (float)(s1 - s0) : 0.f;
        Acat[rowb + 128 + r * 128 + h] = f2bf(out);
    }
}

// ---------------- MFMA GEMM: C = relu(A[NPAD,1152] @ B[1152,128] + bias) -> bf16 ----------------
// BM=64, 4 waves; wave w: rows 0..63, cols w*32..w*32+31 (M_rep=4, N_rep=2)
__global__ __launch_bounds__(256) void mfma_gemm(
    const unsigned short* __restrict__ A,    // [NPAD][KK]
    const unsigned short* __restrict__ Bt,   // [128][KK] (Bt[col][k])
    const float* __restrict__ bias,          // [128]
    unsigned short* __restrict__ Cout)       // [NPAD][128] bf16
{
    __shared__ alignas(16) unsigned short As[64 * 64];    // [row][chunk^ (row&7)] chunks of 8
    __shared__ alignas(16) unsigned short Bs[128 * 64];   // [col][chunk^ (col&7)]
    const int tid = threadIdx.x;
    const int w = tid >> 6, lane = tid & 63;
    const int l15 = lane & 15, lhi = lane >> 4;
    const int row0 = blockIdx.x * 64;

    f32x4 acc[4][2];
    #pragma unroll
    for (int m = 0; m < 4; ++m)
        #pragma unroll
        for (int n = 0; n < 2; ++n) acc[m][n] = (f32x4)(0.f);

    for (int kt = 0; kt < KK / 64; ++kt) {
        const int k0 = kt * 64;
        // stage A tile: 64 rows x 8 chunks(16B). linear LDS dest, pre-swizzled global src (G21)
        #pragma unroll
        for (int i = 0; i < 2; ++i) {
            int q = w * 128 + i * 64 + lane;          // chunk id 0..511
            int row = q >> 3, c = q & 7;
            const unsigned short* g = A + (size_t)(row0 + row) * KK + k0 + ((c ^ (row & 7)) * 8);
            GLDS16(g, &As[(w * 128 + i * 64) * 8]);
        }
        // stage Bt tile: 128 cols x 8 chunks
        #pragma unroll
        for (int i = 0; i < 4; ++i) {
            int q = w * 256 + i * 64 + lane;          // chunk id 0..1023
            int col = q >> 3, c = q & 7;
            const unsigned short* g = Bt + (size_t)col * KK + k0 + ((c ^ (col & 7)) * 8);
            GLDS16(g, &Bs[(w * 256 + i * 64) * 8]);
        }
        __syncthreads();
        #pragma unroll
        for (int j = 0; j < 2; ++j) {
            const int clog = j * 4 + lhi;
            bf16x8 af[4], bfr[2];
            #pragma unroll
            for (int m = 0; m < 4; ++m) {
                int row = m * 16 + l15;
                int ch = clog ^ (row & 7);
                af[m] = *reinterpret_cast<const bf16x8*>(&As[row * 64 + ch * 8]);
            }
            #pragma unroll
            for (int n = 0; n < 2; ++n) {
                int col = w * 32 + n * 16 + l15;
                int ch = clog ^ (col & 7);
                bfr[n] = *reinterpret_cast<const bf16x8*>(&Bs[col * 64 + ch * 8]);
            }
            #pragma unroll
            for (int m = 0; m < 4; ++m)
                #pragma unroll
                for (int n = 0; n < 2; ++n)
                    acc[m][n] = __builtin_amdgcn_mfma_f32_16x16x32_bf16(af[m], bfr[n], acc[m][n], 0, 0, 0);
        }
        __syncthreads();
    }
    // epilogue: C row = m*16 + lhi*4 + r, col = w*32 + n*16 + l15
    #pragma unroll
    for (int n = 0; n < 2; ++n) {
        int col = w * 32 + n * 16 + l15;
        float bv = bias[col];
        #pragma unroll
        for (int m = 0; m < 4; ++m) {
            #pragma unroll
            for (int r = 0; r < 4; ++r) {
                int grow = row0 + m * 16 + lhi * 4 + r;
                if (grow < NN) {
                    float v = fmaxf(acc[m][n][r] + bv, 0.f);
                    Cout[(size_t)grow * 128 + col] = f2bf(v);
                }
            }
        }
    }
}

// ---------------- final FC: out[n] = h3[n] . fc_w + fc_b (h3 already relu'd) ----------------
__global__ __launch_bounds__(256) void final_fc(
    const unsigned short* __restrict__ h, const float* __restrict__ fcw,
    const float* __restrict__ fcb, float* __restrict__ out)
{
    int wid  = (int)((blockIdx.x * 256 + threadIdx.x) >> 6);
    int lane = threadIdx.x & 63;
    if (wid >= NN) return;
    float v = bf2f(h[(size_t)wid * 128 + lane]) * fcw[lane]
            + bf2f(h[(size_t)wid * 128 + 64 + lane]) * fcw[64 + lane];
    #pragma unroll
    for (int off = 32; off > 0; off >>= 1) v += __shfl_down(v, off);
    if (lane == 0) out[wid] = v + fcb[0];
}

extern "C" void kernel_launch(void* const* d_in, const int* in_sizes, int n_in,
                              void* d_out, int out_size, void* d_ws, size_t ws_size,
                              hipStream_t stream) {
    const float* x     = (const float*)d_in[0];
    const int*   ei    = (const int*)d_in[1];
    const int*   etype = (const int*)d_in[2];
    const float* W[3]    = {(const float*)d_in[3], (const float*)d_in[6], (const float*)d_in[9]};
    const float* root[3] = {(const float*)d_in[4], (const float*)d_in[7], (const float*)d_in[10]};
    const float* bias[3] = {(const float*)d_in[5], (const float*)d_in[8], (const float*)d_in[11]};
    const float* fcw = (const float*)d_in[12];
    const float* fcb = (const float*)d_in[13];
    const int* src = ei;
    const int* dst = ei + EE;

    char* ws = (char*)d_ws;
    auto alloc = [&](size_t bytes) { char* p = ws; ws += (bytes + 255) & ~(size_t)255; return p; };
    int* deg       = (int*)alloc(NR * sizeof(int));
    int* cursor    = (int*)alloc(NR * sizeof(int));
    int* segStart  = (int*)alloc((NR + 2) * sizeof(int));
    int* bsum      = (int*)alloc(512 * sizeof(int));
    int* sortedSrc = (int*)alloc(EE * sizeof(int));
    unsigned short* Btg  = (unsigned short*)alloc((size_t)3 * 128 * KK * sizeof(short));
    unsigned short* h1   = (unsigned short*)alloc((size_t)NPAD * 128 * sizeof(short));
    unsigned short* h2   = (unsigned short*)alloc((size_t)NPAD * 128 * sizeof(short));
    unsigned short* Acat = (unsigned short*)alloc((size_t)NPAD * KK * sizeof(short));

    // --- graph preprocessing (per call; graph reused by all 3 layers) ---
    zero_i32<<<(2 * NR + 255) / 256, 256, 0, stream>>>(deg, 2 * NR);   // deg + cursor contiguous
    count_deg<<<(EE + 255) / 256, 256, 0, stream>>>(dst, etype, deg);
    const int nScanBlk = (NR + 1023) / 1024;   // 391
    scan1<<<nScanBlk, 256, 0, stream>>>(deg, segStart, bsum, NR);
    scan2<<<1, 256, 0, stream>>>(bsum, nScanBlk);
    scan3<<<nScanBlk, 256, 0, stream>>>(segStart, bsum, NR);
    set_last<<<1, 1, 0, stream>>>(segStart);
    scatter_edges<<<(EE + 255) / 256, 256, 0, stream>>>(src, dst, etype, segStart, cursor, sortedSrc);

    // --- weights to bf16 transposed panels ---
    const int btThreads = 128 * KK;
    for (int l = 0; l < 3; ++l)
        build_bt<<<(btThreads + 255) / 256, 256, 0, stream>>>(W[l], root[l], Btg + (size_t)l * 128 * KK);

    const int gemmGrid = NPAD / 64;   // 782
    // layer 1 (input fp32 x)
    aggregate<float><<<NPAD, 128, 0, stream>>>(x, segStart, sortedSrc, Acat);
    mfma_gemm<<<gemmGrid, 256, 0, stream>>>(Acat, Btg + 0 * (size_t)128 * KK, bias[0], h1);
    // layer 2
    aggregate<unsigned short><<<NPAD, 128, 0, stream>>>(h1, segStart, sortedSrc, Acat);
    mfma_gemm<<<gemmGrid, 256, 0, stream>>>(Acat, Btg + 1 * (size_t)128 * KK, bias[1], h2);
    // layer 3
    aggregate<unsigned short><<<NPAD, 128, 0, stream>>>(h2, segStart, sortedSrc, Acat);
    mfma_gemm<<<gemmGrid, 256, 0, stream>>>(Acat, Btg + 2 * (size_t)128 * KK, bias[2], h1);

    final_fc<<<(NN * 64 + 255) / 256, 256, 0, stream>>>(h1, fcw, fcb, (float*)d_out);
}